// Round 13
// baseline (45.401 us; speedup 1.0000x reference)
//
#include <hip/hip_runtime.h>
#include <math.h>

#define NROWS 8192
#define DIN   256
#define NH    8
#define NC    128
#define DOUT  256

typedef unsigned short ushort_t;
typedef __attribute__((ext_vector_type(8))) short bf16x8;
typedef __attribute__((ext_vector_type(4))) float f32x4;
typedef __attribute__((ext_vector_type(8))) unsigned short u16x8;

static __device__ __forceinline__ ushort_t f2bf(float f) {
  union { float f; unsigned u; } v; v.f = f;
  unsigned r = v.u + 0x7fffu + ((v.u >> 16) & 1u);
  return (ushort_t)(r >> 16);
}
static __device__ __forceinline__ float bf2f(ushort_t h) {
  union { unsigned u; float f; } v; v.u = ((unsigned)h) << 16;
  return v.f;
}

#define MFMA16(a, b, c) __builtin_amdgcn_mfma_f32_16x16x32_bf16((a), (b), (c), 0, 0, 0)
#define GLOAD_LDS16(g, l)                                                     \
  __builtin_amdgcn_global_load_lds(                                           \
      (const __attribute__((address_space(1))) void*)(g),                     \
      (__attribute__((address_space(3))) void*)(l), 16, 0, 0)

// ---------------------------------------------------------------------------
// Merged prep (grid 1536 x 256) — byte-identical to r9/r12.
// ---------------------------------------------------------------------------
__global__ __launch_bounds__(256) void prep_kernel(
    const float* __restrict__ Wq, const float* __restrict__ ctrs,
    const float* __restrict__ Wo, const float* __restrict__ Wv,
    const float* __restrict__ Ov, ushort_t* __restrict__ wcvtT,
    ushort_t* __restrict__ ctr3T, float* __restrict__ cbias,
    ushort_t* __restrict__ WoT, ushort_t* __restrict__ W2bT) {
  int bid = blockIdx.x;
  int t = threadIdx.x;
  if (bid < 512) {
    int j = bid, k = t;
    int h = j >> 6, p = j & 63;
    float v = Wq[((size_t)k * 64 + p) * 8 + h];
    ushort_t hi = f2bf(v), lo = f2bf(v - bf2f(hi));
    wcvtT[(size_t)j * 512 + k]       = hi;
    wcvtT[(size_t)j * 512 + 256 + k] = lo;
  } else if (bid < 768) {
    int idx = (bid - 512) * 4 + (t >> 6);   // h*128+c
    int p = t & 63;
    float v = ctrs[(size_t)idx * 64 + p];
    float sq = v * v;
    #pragma unroll
    for (int off = 32; off >= 1; off >>= 1) sq += __shfl_xor(sq, off, 64);
    if (p == 0) cbias[idx] = -sq;
    ushort_t hi = f2bf(v), lo = f2bf(v - bf2f(hi));
    ctr3T[(size_t)idx * 192 + p]       = hi;
    ctr3T[(size_t)idx * 192 + 64 + p]  = lo;
    ctr3T[(size_t)idx * 192 + 128 + p] = hi;
  } else if (bid < 1280) {
    int k = bid - 768;    // 0..511
    int n = t;            // 0..255
    WoT[(size_t)n * 512 + k] = f2bf(Wo[(size_t)k * 256 + n]);
  } else {
    int b = (bid - 1280) * 4 + (t >> 6);   // h*128 + c
    int p = t & 63;
    int h = b >> 7, c = b & 127;
    const float* wv = Wv + (size_t)b * 4096;
    float acc = 0.f;
    #pragma unroll 8
    for (int g = 0; g < 64; ++g) acc += wv[g * 64 + p];
    W2bT[((size_t)h * 128 + p) * 128 + c]      = f2bf(acc);
    W2bT[((size_t)h * 128 + 64 + p) * 128 + c] = f2bf(Ov[(size_t)b * 64 + p]);
  }
}

// ---------------------------------------------------------------------------
// Fused-pair + out-tail: per block (head h, 128 tokens):
//   xin = x@Wq (split-bf16, 4 chunks) -> logits (K=192) -> softmax ->
//   T = a@W2 (K=128) -> ho = xin*t1+t2 -> swizzled ho in LDS ->
//   out[vbase..vbase+16) = ho_view(16x512) @ WoT^T   (final GEMM is
//   block-local: view-row m = head m>>10, tokens 8(m&1023)..+8).
// Tail k-order identical to old gemm2 -> bit-identical output.
// LDS 70.1 KB -> 2 blocks/CU.
// ---------------------------------------------------------------------------
__global__ __launch_bounds__(256, 2) void fused_pair_kernel(
    const float* __restrict__ x,          // [8192][256] f32
    const ushort_t* __restrict__ wcvtT,   // [512][512] hi|lo
    const ushort_t* __restrict__ ctr3T,   // [1024][192]
    const float* __restrict__ cbias,      // [1024]
    const ushort_t* __restrict__ W2bT,    // [1024][128]
    const ushort_t* __restrict__ WoT,     // [256][512]
    float* __restrict__ out) {            // [8192][256]
  __shared__ __align__(16) char Au_raw[36864];
  __shared__ char B0lds[16384];
  __shared__ char B1lds[16384];
  __shared__ float cb_lds[128];

  ushort_t* Axh = (ushort_t*)Au_raw;             // [128][72]
  ushort_t* Axl = (ushort_t*)(Au_raw + 18432);   // [128][72]
  ushort_t* A1  = (ushort_t*)Au_raw;             // [128][136]
  ushort_t* A2  = (ushort_t*)Au_raw;             // [128][136]

  const int t = threadIdx.x;
  const int w = t >> 6, l = t & 63;
  const int lr = l & 15, lk = l >> 4;
  const int h = blockIdx.x >> 6;                 // 8 heads x 64 pairs
  const int n0 = (blockIdx.x & 63) * 128;

#define STAGE_B(BUF, SRC, LDB, KOFF)                                          \
  {                                                                           \
    _Pragma("unroll")                                                         \
    for (int i = 0; i < 4; ++i) {                                             \
      int q = (i * 4 + w) * 64 + l;                                           \
      int row = q >> 3, s = q & 7;                                            \
      GLOAD_LDS16((SRC) + (size_t)(h * 128 + row) * (LDB) + (KOFF) +          \
                      ((s ^ (row & 7)) << 3),                                 \
                  (char*)(BUF) + (size_t)(i * 4 + w) * 1024);                 \
    }                                                                         \
  }

#define STAGE_BX(BUF, KC)                                                     \
  {                                                                           \
    _Pragma("unroll")                                                         \
    for (int i = 0; i < 4; ++i) {                                             \
      int q = (i * 4 + w) * 64 + l;                                           \
      int row = q >> 3, s = q & 7;                                            \
      int sw = (s ^ (row & 7)) << 3;                                          \
      int jj = h * 64 + (row & 63);                                           \
      int koff = (row < 64 ? 0 : 256) + (KC) * 64 + sw;                       \
      GLOAD_LDS16(wcvtT + (size_t)jj * 512 + koff,                            \
                  (char*)(BUF) + (size_t)(i * 4 + w) * 1024);                 \
    }                                                                         \
  }

#define MFMA_STEP(BUF, ACC0, ACC1, KBASE, ASPLIT)                             \
  {                                                                           \
    _Pragma("unroll")                                                         \
    for (int kk = 0; kk < 2; ++kk) {                                          \
      int klog = (KBASE) + kk * 32 + lk * 8;                                  \
      int kp = (ASPLIT) ? (klog < 64 ? klog : klog - 64) : klog;              \
      bf16x8 af0 = *(const bf16x8*)&A1[(w * 16 + lr) * 136 + kp];             \
      bf16x8 af1 = *(const bf16x8*)&A1[(64 + w * 16 + lr) * 136 + kp];        \
      _Pragma("unroll")                                                       \
      for (int cj = 0; cj < 8; ++cj) {                                        \
        int brow = cj * 16 + lr;                                              \
        int slot = (kk * 4 + lk) ^ (brow & 7);                                \
        bf16x8 bfr =                                                          \
            *(const bf16x8*)((const char*)(BUF) + brow * 128 + slot * 16);    \
        (ACC0)[cj] = MFMA16(af0, bfr, (ACC0)[cj]);                            \
        (ACC1)[cj] = MFMA16(af1, bfr, (ACC1)[cj]);                            \
      }                                                                       \
    }                                                                         \
  }

#define MFMAX(BUF)                                                            \
  {                                                                           \
    _Pragma("unroll")                                                         \
    for (int kk = 0; kk < 2; ++kk) {                                          \
      bf16x8 ah0 = *(const bf16x8*)&Axh[(w * 16 + lr) * 72 + kk * 32 + lk * 8];     \
      bf16x8 al0 = *(const bf16x8*)&Axl[(w * 16 + lr) * 72 + kk * 32 + lk * 8];     \
      bf16x8 ah1 = *(const bf16x8*)&Axh[(64 + w * 16 + lr) * 72 + kk * 32 + lk * 8];\
      bf16x8 al1 = *(const bf16x8*)&Axl[(64 + w * 16 + lr) * 72 + kk * 32 + lk * 8];\
      _Pragma("unroll")                                                       \
      for (int cj = 0; cj < 4; ++cj) {                                        \
        int rh = cj * 16 + lr;                                                \
        int slot = (kk * 4 + lk) ^ (rh & 7);                                  \
        bf16x8 bh = *(const bf16x8*)((const char*)(BUF) + rh * 128 + slot * 16);\
        bf16x8 bl = *(const bf16x8*)((const char*)(BUF) + (64 + rh) * 128 + slot * 16);\
        acc_x0[cj] = MFMA16(ah0, bh, acc_x0[cj]);                             \
        acc_x0[cj] = MFMA16(al0, bh, acc_x0[cj]);                             \
        acc_x0[cj] = MFMA16(ah0, bl, acc_x0[cj]);                             \
        acc_x1[cj] = MFMA16(ah1, bh, acc_x1[cj]);                             \
        acc_x1[cj] = MFMA16(al1, bh, acc_x1[cj]);                             \
        acc_x1[cj] = MFMA16(ah1, bl, acc_x1[cj]);                             \
      }                                                                       \
    }                                                                         \
  }

#define BAR() __builtin_amdgcn_s_barrier()
#define SCHED() __builtin_amdgcn_sched_barrier(0)
#define DRAIN_LGKM()                                                          \
  { asm volatile("s_waitcnt lgkmcnt(0)" ::: "memory"); SCHED(); }

  const int xrow = t >> 2;                 // 0..63
  const int xseg = (t & 3) << 4;           // 0/16/32/48
  const float* xb0 = x + (size_t)(n0 + xrow) * 256 + xseg;
  const float* xb1 = xb0 + 64 * 256;
  float4 xr[8];

#define LOAD_X(KC)                                                            \
  {                                                                           \
    _Pragma("unroll")                                                         \
    for (int j = 0; j < 4; ++j) xr[j]     = *(const float4*)(xb0 + (KC) * 64 + j * 4); \
    _Pragma("unroll")                                                         \
    for (int j = 0; j < 4; ++j) xr[4 + j] = *(const float4*)(xb1 + (KC) * 64 + j * 4); \
  }

#define CVT_AX()                                                              \
  {                                                                           \
    _Pragma("unroll")                                                         \
    for (int hf = 0; hf < 2; ++hf) {                                          \
      u16x8 hv0, hv1, lv0, lv1;                                               \
      _Pragma("unroll")                                                       \
      for (int j = 0; j < 2; ++j) {                                           \
        float f4[8] = {xr[hf*4 + j*2].x, xr[hf*4 + j*2].y, xr[hf*4 + j*2].z,  \
                       xr[hf*4 + j*2].w, xr[hf*4 + j*2 + 1].x,                \
                       xr[hf*4 + j*2 + 1].y, xr[hf*4 + j*2 + 1].z,            \
                       xr[hf*4 + j*2 + 1].w};                                 \
        _Pragma("unroll")                                                     \
        for (int e = 0; e < 8; ++e) {                                         \
          ushort_t hi = f2bf(f4[e]);                                          \
          if (j == 0) { hv0[e] = hi; lv0[e] = f2bf(f4[e] - bf2f(hi)); }       \
          else        { hv1[e] = hi; lv1[e] = f2bf(f4[e] - bf2f(hi)); }       \
        }                                                                     \
      }                                                                       \
      int ro = hf * 64 + xrow;                                                \
      *(u16x8*)&Axh[ro * 72 + xseg]     = hv0;                                \
      *(u16x8*)&Axh[ro * 72 + xseg + 8] = hv1;                                \
      *(u16x8*)&Axl[ro * 72 + xseg]     = lv0;                                \
      *(u16x8*)&Axl[ro * 72 + xseg + 8] = lv1;                                \
    }                                                                         \
  }

#define SOFTMAX(ACC, ROFF)                                                    \
  {                                                                           \
    float cbv[8];                                                             \
    _Pragma("unroll")                                                         \
    for (int cj = 0; cj < 8; ++cj) cbv[cj] = cb_lds[cj * 16 + lr];            \
    _Pragma("unroll")                                                         \
    for (int r = 0; r < 4; ++r) {                                             \
      float v[8];                                                             \
      float m = -1e30f;                                                       \
      _Pragma("unroll")                                                       \
      for (int cj = 0; cj < 8; ++cj) {                                        \
        v[cj] = 2.f * (ACC)[cj][r] + cbv[cj];                                 \
        m = fmaxf(m, v[cj]);                                                  \
      }                                                                       \
      m = fmaxf(m, __shfl_xor(m, 1, 64));                                     \
      m = fmaxf(m, __shfl_xor(m, 2, 64));                                     \
      m = fmaxf(m, __shfl_xor(m, 4, 64));                                     \
      m = fmaxf(m, __shfl_xor(m, 8, 64));                                     \
      float s = 0.f;                                                          \
      _Pragma("unroll")                                                       \
      for (int cj = 0; cj < 8; ++cj) {                                        \
        v[cj] = __expf(v[cj] - m);                                            \
        s += v[cj];                                                           \
      }                                                                       \
      s += __shfl_xor(s, 1, 64);                                              \
      s += __shfl_xor(s, 2, 64);                                              \
      s += __shfl_xor(s, 4, 64);                                              \
      s += __shfl_xor(s, 8, 64);                                              \
      float inv = 1.f / s;                                                    \
      int row = (ROFF) + w * 16 + lk * 4 + r;                                 \
      _Pragma("unroll")                                                       \
      for (int cj = 0; cj < 8; ++cj)                                          \
        A2[row * 136 + cj * 16 + lr] = f2bf(v[cj] * inv);                     \
    }                                                                         \
  }

  // ---- prologue ----
  cb_lds[t & 127] = cbias[h * 128 + (t & 127)];
  LOAD_X(0);
  STAGE_BX(B0lds, 0);
  SCHED();                                 // pin B0 before B1 (vmcnt counting)
  STAGE_BX(B1lds, 1);
  SCHED();
  f32x4 acc_x0[4], acc_x1[4];
  #pragma unroll
  for (int cj = 0; cj < 4; ++cj) {
    acc_x0[cj] = (f32x4){0.f, 0.f, 0.f, 0.f};
    acc_x1[cj] = (f32x4){0.f, 0.f, 0.f, 0.f};
  }
  CVT_AX();                                // consume x0 (leaves B0,B1)
  SCHED();
  LOAD_X(1);                               // Q: [B0:4, B1:4, x1:8]
  asm volatile("s_waitcnt vmcnt(12)" ::: "memory");  // B0 done
  DRAIN_LGKM(); BAR(); SCHED();
  // chunk 0
  MFMAX(B0lds);
  DRAIN_LGKM(); BAR(); SCHED();
  STAGE_BX(B0lds, 2);                      // Q: [B1, x1, B2]
  SCHED();
  CVT_AX();                                // consume x1 -> forces B1 done
  SCHED();
  LOAD_X(2);                               // Q: [B2:4, x2:8]
  DRAIN_LGKM(); BAR(); SCHED();
  // chunk 1
  MFMAX(B1lds);
  DRAIN_LGKM(); BAR(); SCHED();
  STAGE_BX(B1lds, 3);                      // Q: [B2, x2, B3]
  SCHED();
  CVT_AX();                                // consume x2 -> forces B2 done
  SCHED();
  LOAD_X(3);                               // Q: [B3:4, x3:8]
  DRAIN_LGKM(); BAR(); SCHED();
  // chunk 2
  MFMAX(B0lds);
  DRAIN_LGKM(); BAR(); SCHED();
  STAGE_B(B0lds, ctr3T, 192, 0);           // Q: [B3, x3, ctr0]
  SCHED();
  CVT_AX();                                // consume x3 -> forces B3 done
  DRAIN_LGKM(); BAR(); SCHED();
  // chunk 3
  MFMAX(B1lds);
  DRAIN_LGKM(); BAR(); SCHED();            // B1lds, Ax free

  // write A1 (xin hi|lo) from acc_x — own wave's rows (Ax now dead)
  STAGE_B(B1lds, ctr3T, 192, 64);          // Q: [ctr0:4, ctr64:4]
  #pragma unroll
  for (int cj = 0; cj < 4; ++cj) {
    #pragma unroll
    for (int r = 0; r < 4; ++r) {
      int row = w * 16 + lk * 4 + r;
      int p = cj * 16 + lr;
      float v0 = acc_x0[cj][r];
      ushort_t hi0 = f2bf(v0);
      A1[row * 136 + p] = hi0;
      A1[row * 136 + 64 + p] = f2bf(v0 - bf2f(hi0));
      float v1 = acc_x1[cj][r];
      ushort_t hi1 = f2bf(v1);
      A1[(64 + row) * 136 + p] = hi1;
      A1[(64 + row) * 136 + 64 + p] = f2bf(v1 - bf2f(hi1));
    }
  }
  asm volatile("s_waitcnt vmcnt(4)" ::: "memory");  // ctr0 done
  DRAIN_LGKM(); BAR(); SCHED();

  // ---- logits: K=192 ----
  f32x4 acc0[8], acc1[8];
  #pragma unroll
  for (int cj = 0; cj < 8; ++cj) {
    acc0[cj] = (f32x4){0.f, 0.f, 0.f, 0.f};
    acc1[cj] = (f32x4){0.f, 0.f, 0.f, 0.f};
  }
  MFMA_STEP(B0lds, acc0, acc1, 0, 1);      // L0
  DRAIN_LGKM(); BAR(); SCHED();
  STAGE_B(B0lds, ctr3T, 192, 128);         // Q: [ctr64, ctr128]
  asm volatile("s_waitcnt vmcnt(4)" ::: "memory");
  BAR(); SCHED();
  MFMA_STEP(B1lds, acc0, acc1, 64, 1);     // L1
  DRAIN_LGKM(); BAR(); SCHED();
  STAGE_B(B1lds, W2bT, 128, 0);            // Q: [ctr128, W2k0]
  asm volatile("s_waitcnt vmcnt(4)" ::: "memory");
  BAR(); SCHED();
  MFMA_STEP(B0lds, acc0, acc1, 128, 1);    // L2
  DRAIN_LGKM();                            // A1 reads landed

  // ---- softmax (rows within wave; A2 overwrites A1 at own-wave rows) ----
  SOFTMAX(acc0, 0);
  SOFTMAX(acc1, 64);
  DRAIN_LGKM();
  BAR(); SCHED();        // safe to overwrite B0lds

  f32x4 accT0[8], accT1[8];
  #pragma unroll
  for (int cj = 0; cj < 8; ++cj) {
    accT0[cj] = (f32x4){0.f, 0.f, 0.f, 0.f};
    accT1[cj] = (f32x4){0.f, 0.f, 0.f, 0.f};
  }
  STAGE_B(B0lds, W2bT, 128, 64);           // Q: [W2k0, W2k64]
  asm volatile("s_waitcnt vmcnt(4)" ::: "memory");
  BAR(); SCHED();
  MFMA_STEP(B1lds, accT0, accT1, 0, 0);    // T0
  DRAIN_LGKM();
  asm volatile("s_waitcnt vmcnt(0)" ::: "memory");
  BAR(); SCHED();
  MFMA_STEP(B0lds, accT0, accT1, 64, 0);   // T1

  // ---- epilogue: ho = xin(f32 regs)*t1 + t2 ; SWIZZLED ho tile in B1lds ----
  // layout: byte = row*128 + ((p>>3) ^ ((row>>3)&7))*16 + (p&7)*2
  #pragma unroll
  for (int cj = 0; cj < 4; ++cj) {
    #pragma unroll
    for (int r = 0; r < 4; ++r) {
      int row0 = w * 16 + lk * 4 + r;
      int slotp = cj * 2 + (lr >> 3);
      int sw = (slotp ^ ((row0 >> 3) & 7));   // same for row0+64
      float hov0 = acc_x0[cj][r] * accT0[cj][r] + accT0[cj + 4][r];
      *(ushort_t*)((char*)B1lds + row0 * 128 + sw * 16 + (lr & 7) * 2) =
          f2bf(hov0);
      float hov1 = acc_x1[cj][r] * accT1[cj][r] + accT1[cj + 4][r];
      *(ushort_t*)((char*)B1lds + (64 + row0) * 128 + sw * 16 + (lr & 7) * 2) =
          f2bf(hov1);
    }
  }
  DRAIN_LGKM(); BAR(); SCHED();

  // ---- tail: out rows [vbase, vbase+16) = ho_view(16x512) @ WoT^T ----
  // view-row lr <-> tokens 8*lr..8*lr+8 of this block; k = (j<<6)|p.
  // A-frag (ks step): token row = 8*lr + (ks>>1), p = (ks&1)*32 + lk*8.
  {
    const int vbase = (h << 10) + (blockIdx.x & 63) * 16;
    f32x4 accO[4];
    #pragma unroll
    for (int c = 0; c < 4; ++c) accO[c] = (f32x4){0.f, 0.f, 0.f, 0.f};
    #pragma unroll
    for (int ks = 0; ks < 16; ++ks) {
      int rowt = 8 * lr + (ks >> 1);
      int slot = (((ks & 1) * 4 + lk) ^ (lr & 7));
      bf16x8 af = *(const bf16x8*)((const char*)B1lds + rowt * 128 + slot * 16);
      #pragma unroll
      for (int c = 0; c < 4; ++c) {
        int n = (w * 4 + c) * 16 + lr;
        bf16x8 bfr = *(const bf16x8*)(WoT + (size_t)n * 512 + ks * 32 + lk * 8);
        accO[c] = MFMA16(af, bfr, accO[c]);
      }
    }
    #pragma unroll
    for (int c = 0; c < 4; ++c) {
      #pragma unroll
      for (int r = 0; r < 4; ++r) {
        out[(size_t)(vbase + lk * 4 + r) * 256 + (w * 4 + c) * 16 + lr] =
            accO[c][r];
      }
    }
  }
#undef STAGE_B
#undef STAGE_BX
#undef MFMA_STEP
#undef MFMAX
#undef BAR
#undef SCHED
#undef DRAIN_LGKM
#undef LOAD_X
#undef CVT_AX
#undef SOFTMAX
}

// ---------------------------------------------------------------------------
extern "C" void kernel_launch(void* const* d_in, const int* in_sizes, int n_in,
                              void* d_out, int out_size, void* d_ws, size_t ws_size,
                              hipStream_t stream) {
  (void)in_sizes; (void)n_in; (void)out_size; (void)ws_size;
  const float* x    = (const float*)d_in[0];
  const float* ctrs = (const float*)d_in[1];
  const float* Wv   = (const float*)d_in[2];
  const float* Ov   = (const float*)d_in[3];
  const float* Wq   = (const float*)d_in[4];
  const float* Wo   = (const float*)d_in[5];
  float* out = (float*)d_out;

  char* wsb = (char*)d_ws;
  ushort_t* wcvtT = (ushort_t*)wsb;                   // [0, 524288)
  ushort_t* ctr3T = (ushort_t*)(wsb + 524288);        // [524288, 917504)
  float*    cb    = (float*)   (wsb + 917504);        // [917504, 921600)
  ushort_t* W2bT  = (ushort_t*)(wsb + 921600);        // [921600, 1183744)
  ushort_t* WoT   = (ushort_t*)(wsb + 1183744);       // [1183744, 1445888)

  prep_kernel<<<1536, 256, 0, stream>>>(Wq, ctrs, Wo, Wv, Ov,
                                        wcvtT, ctr3T, cb, WoT, W2bT);
  fused_pair_kernel<<<512, 256, 0, stream>>>(x, wcvtT, ctr3T, cb, W2bT, WoT,
                                             out);
}

// Round 14
// 42.908 us; speedup vs baseline: 1.0581x; 1.0581x over previous
//
#include <hip/hip_runtime.h>
#include <math.h>

#define NROWS 8192
#define DIN   256
#define NH    8
#define NC    128
#define DOUT  256

typedef unsigned short ushort_t;
typedef __attribute__((ext_vector_type(8))) short bf16x8;
typedef __attribute__((ext_vector_type(4))) float f32x4;
typedef __attribute__((ext_vector_type(8))) unsigned short u16x8;

static __device__ __forceinline__ ushort_t f2bf(float f) {
  union { float f; unsigned u; } v; v.f = f;
  unsigned r = v.u + 0x7fffu + ((v.u >> 16) & 1u);
  return (ushort_t)(r >> 16);
}
static __device__ __forceinline__ float bf2f(ushort_t h) {
  union { unsigned u; float f; } v; v.u = ((unsigned)h) << 16;
  return v.f;
}

#define MFMA16(a, b, c) __builtin_amdgcn_mfma_f32_16x16x32_bf16((a), (b), (c), 0, 0, 0)
#define GLOAD_LDS16(g, l)                                                     \
  __builtin_amdgcn_global_load_lds(                                           \
      (const __attribute__((address_space(1))) void*)(g),                     \
      (__attribute__((address_space(3))) void*)(l), 16, 0, 0)

// ---------------------------------------------------------------------------
// Merged prep (grid 1536 x 256) — byte-identical to r12.
// ---------------------------------------------------------------------------
__global__ __launch_bounds__(256) void prep_kernel(
    const float* __restrict__ Wq, const float* __restrict__ ctrs,
    const float* __restrict__ Wo, const float* __restrict__ Wv,
    const float* __restrict__ Ov, ushort_t* __restrict__ wcvtT,
    ushort_t* __restrict__ ctr3T, float* __restrict__ cbias,
    ushort_t* __restrict__ WoT, ushort_t* __restrict__ W2bT) {
  int bid = blockIdx.x;
  int t = threadIdx.x;
  if (bid < 512) {
    int j = bid, k = t;
    int h = j >> 6, p = j & 63;
    float v = Wq[((size_t)k * 64 + p) * 8 + h];
    ushort_t hi = f2bf(v), lo = f2bf(v - bf2f(hi));
    wcvtT[(size_t)j * 512 + k]       = hi;
    wcvtT[(size_t)j * 512 + 256 + k] = lo;
  } else if (bid < 768) {
    int idx = (bid - 512) * 4 + (t >> 6);   // h*128+c
    int p = t & 63;
    float v = ctrs[(size_t)idx * 64 + p];
    float sq = v * v;
    #pragma unroll
    for (int off = 32; off >= 1; off >>= 1) sq += __shfl_xor(sq, off, 64);
    if (p == 0) cbias[idx] = -sq;
    ushort_t hi = f2bf(v), lo = f2bf(v - bf2f(hi));
    ctr3T[(size_t)idx * 192 + p]       = hi;
    ctr3T[(size_t)idx * 192 + 64 + p]  = lo;
    ctr3T[(size_t)idx * 192 + 128 + p] = hi;
  } else if (bid < 1280) {
    int k = bid - 768;    // 0..511
    int n = t;            // 0..255
    WoT[(size_t)n * 512 + k] = f2bf(Wo[(size_t)k * 256 + n]);
  } else {
    int b = (bid - 1280) * 4 + (t >> 6);   // h*128 + c
    int p = t & 63;
    int h = b >> 7, c = b & 127;
    const float* wv = Wv + (size_t)b * 4096;
    float acc = 0.f;
    #pragma unroll 8
    for (int g = 0; g < 64; ++g) acc += wv[g * 64 + p];
    W2bT[((size_t)h * 128 + p) * 128 + c]      = f2bf(acc);
    W2bT[((size_t)h * 128 + 64 + p) * 128 + c] = f2bf(Ov[(size_t)b * 64 + p]);
  }
}

// ---------------------------------------------------------------------------
// gemm2 — byte-identical to r12 (BM=64, 512 blocks, 2/CU).
// ---------------------------------------------------------------------------
__global__ __launch_bounds__(256) void gemm2_kernel(
    const ushort_t* __restrict__ A, const ushort_t* __restrict__ Bt,
    float* __restrict__ out) {
  __shared__ ushort_t At[64 * 64];
  __shared__ ushort_t Bl[64 * 64];
  const int t = threadIdx.x;
  const int w = t >> 6, l = t & 63;
  const int wr = w >> 1, wc = w & 1;
  const int m0 = (blockIdx.x >> 2) * 64, n0 = (blockIdx.x & 3) * 64;
  const int lr = l & 15, lk = l >> 4;

  f32x4 acc[2][2];
  #pragma unroll
  for (int a = 0; a < 2; ++a)
    #pragma unroll
    for (int b = 0; b < 2; ++b) acc[a][b] = (f32x4){0.f, 0.f, 0.f, 0.f};

  for (int k0 = 0; k0 < 512; k0 += 64) {
    #pragma unroll
    for (int i = 0; i < 2; ++i) {
      int q = (i * 4 + w) * 64 + l;
      int row = q >> 3, s = q & 7;
      int kl = k0 + ((s ^ (row & 7)) << 3);
      GLOAD_LDS16(A + (size_t)(m0 + row) * 512 + kl,
                  (char*)At + (size_t)(i * 4 + w) * 1024);
    }
    #pragma unroll
    for (int i = 0; i < 2; ++i) {
      int q = (i * 4 + w) * 64 + l;
      int row = q >> 3, s = q & 7;
      int kl = k0 + ((s ^ (row & 7)) << 3);
      GLOAD_LDS16(Bt + (size_t)(n0 + row) * 512 + kl,
                  (char*)Bl + (size_t)(i * 4 + w) * 1024);
    }
    __syncthreads();
    #pragma unroll
    for (int kk = 0; kk < 2; ++kk) {
      bf16x8 af[2], bfr[2];
      #pragma unroll
      for (int a = 0; a < 2; ++a) {
        int row = wr * 32 + a * 16 + lr;
        int s = (kk * 4 + lk) ^ (row & 7);
        af[a] = *(const bf16x8*)((const char*)At + row * 128 + s * 16);
      }
      #pragma unroll
      for (int b = 0; b < 2; ++b) {
        int row = wc * 32 + b * 16 + lr;
        int s = (kk * 4 + lk) ^ (row & 7);
        bfr[b] = *(const bf16x8*)((const char*)Bl + row * 128 + s * 16);
      }
      #pragma unroll
      for (int a = 0; a < 2; ++a)
        #pragma unroll
        for (int b = 0; b < 2; ++b)
          acc[a][b] = MFMA16(af[a], bfr[b], acc[a][b]);
    }
    __syncthreads();
  }
  #pragma unroll
  for (int a = 0; a < 2; ++a) {
    #pragma unroll
    for (int b = 0; b < 2; ++b) {
      #pragma unroll
      for (int r = 0; r < 4; ++r) {
        int rowg = m0 + wr * 32 + a * 16 + lk * 4 + r;
        int colg = n0 + wc * 32 + b * 16 + lr;
        out[(size_t)rowg * 256 + colg] = acc[a][b][r];
      }
    }
  }
}

// ---------------------------------------------------------------------------
// Fused-pair v3 (10-region schedule): all A-side LDS (Ax/A1/A2) is WAVE-LOCAL
// (rows w*16.. / xrow partitions), so barriers are needed only around the
// cross-wave B staging. Each region = {STAGE(next-buf); wave-local work;
// MFMA(cur-buf); waitcnt(vm0,lgkm0); barrier} — ONE barrier per region
// (was 2). Union-overlap hazards (A1 over other waves' Ax, A2 over A1)
// all sit across region barriers. FP order identical to r12.
// LDS 70.1 KB -> 2 blocks/CU.
// ---------------------------------------------------------------------------
__global__ __launch_bounds__(256, 2) void fused_pair_kernel(
    const float* __restrict__ x,          // [8192][256] f32
    const ushort_t* __restrict__ wcvtT,   // [512][512] hi|lo
    const ushort_t* __restrict__ ctr3T,   // [1024][192]
    const float* __restrict__ cbias,      // [1024]
    const ushort_t* __restrict__ W2bT,    // [1024][128]
    ushort_t* __restrict__ ho2) {         // flat (h,N,p)
  __shared__ __align__(16) char Au_raw[36864];
  __shared__ char B0lds[16384];
  __shared__ char B1lds[16384];
  __shared__ float cb_lds[128];

  ushort_t* Axh = (ushort_t*)Au_raw;             // [128][72]
  ushort_t* Axl = (ushort_t*)(Au_raw + 18432);   // [128][72]
  ushort_t* A1  = (ushort_t*)Au_raw;             // [128][136]
  ushort_t* A2  = (ushort_t*)Au_raw;             // [128][136]

  const int t = threadIdx.x;
  const int w = t >> 6, l = t & 63;
  const int lr = l & 15, lk = l >> 4;
  const int h = blockIdx.x >> 6;                 // 8 heads x 64 pairs
  const int n0 = (blockIdx.x & 63) * 128;

#define STAGE_B(BUF, SRC, LDB, KOFF)                                          \
  {                                                                           \
    _Pragma("unroll")                                                         \
    for (int i = 0; i < 4; ++i) {                                             \
      int q = (i * 4 + w) * 64 + l;                                           \
      int row = q >> 3, s = q & 7;                                            \
      GLOAD_LDS16((SRC) + (size_t)(h * 128 + row) * (LDB) + (KOFF) +          \
                      ((s ^ (row & 7)) << 3),                                 \
                  (char*)(BUF) + (size_t)(i * 4 + w) * 1024);                 \
    }                                                                         \
  }

#define STAGE_BX(BUF, KC)                                                     \
  {                                                                           \
    _Pragma("unroll")                                                         \
    for (int i = 0; i < 4; ++i) {                                             \
      int q = (i * 4 + w) * 64 + l;                                           \
      int row = q >> 3, s = q & 7;                                            \
      int sw = (s ^ (row & 7)) << 3;                                          \
      int jj = h * 64 + (row & 63);                                           \
      int koff = (row < 64 ? 0 : 256) + (KC) * 64 + sw;                       \
      GLOAD_LDS16(wcvtT + (size_t)jj * 512 + koff,                            \
                  (char*)(BUF) + (size_t)(i * 4 + w) * 1024);                 \
    }                                                                         \
  }

#define MFMA_STEP(BUF, ACC0, ACC1, KBASE, ASPLIT)                             \
  {                                                                           \
    _Pragma("unroll")                                                         \
    for (int kk = 0; kk < 2; ++kk) {                                          \
      int klog = (KBASE) + kk * 32 + lk * 8;                                  \
      int kp = (ASPLIT) ? (klog < 64 ? klog : klog - 64) : klog;              \
      bf16x8 af0 = *(const bf16x8*)&A1[(w * 16 + lr) * 136 + kp];             \
      bf16x8 af1 = *(const bf16x8*)&A1[(64 + w * 16 + lr) * 136 + kp];        \
      _Pragma("unroll")                                                       \
      for (int cj = 0; cj < 8; ++cj) {                                        \
        int brow = cj * 16 + lr;                                              \
        int slot = (kk * 4 + lk) ^ (brow & 7);                                \
        bf16x8 bfr =                                                          \
            *(const bf16x8*)((const char*)(BUF) + brow * 128 + slot * 16);    \
        (ACC0)[cj] = MFMA16(af0, bfr, (ACC0)[cj]);                            \
        (ACC1)[cj] = MFMA16(af1, bfr, (ACC1)[cj]);                            \
      }                                                                       \
    }                                                                         \
  }

#define MFMAX(BUF)                                                            \
  {                                                                           \
    _Pragma("unroll")                                                         \
    for (int kk = 0; kk < 2; ++kk) {                                          \
      bf16x8 ah0 = *(const bf16x8*)&Axh[(w * 16 + lr) * 72 + kk * 32 + lk * 8];     \
      bf16x8 al0 = *(const bf16x8*)&Axl[(w * 16 + lr) * 72 + kk * 32 + lk * 8];     \
      bf16x8 ah1 = *(const bf16x8*)&Axh[(64 + w * 16 + lr) * 72 + kk * 32 + lk * 8];\
      bf16x8 al1 = *(const bf16x8*)&Axl[(64 + w * 16 + lr) * 72 + kk * 32 + lk * 8];\
      _Pragma("unroll")                                                       \
      for (int cj = 0; cj < 4; ++cj) {                                        \
        int rh = cj * 16 + lr;                                                \
        int slot = (kk * 4 + lk) ^ (rh & 7);                                  \
        bf16x8 bh = *(const bf16x8*)((const char*)(BUF) + rh * 128 + slot * 16);\
        bf16x8 bl = *(const bf16x8*)((const char*)(BUF) + (64 + rh) * 128 + slot * 16);\
        acc_x0[cj] = MFMA16(ah0, bh, acc_x0[cj]);                             \
        acc_x0[cj] = MFMA16(al0, bh, acc_x0[cj]);                             \
        acc_x0[cj] = MFMA16(ah0, bl, acc_x0[cj]);                             \
        acc_x1[cj] = MFMA16(ah1, bh, acc_x1[cj]);                             \
        acc_x1[cj] = MFMA16(al1, bh, acc_x1[cj]);                             \
        acc_x1[cj] = MFMA16(ah1, bl, acc_x1[cj]);                             \
      }                                                                       \
    }                                                                         \
  }

#define BAR() __builtin_amdgcn_s_barrier()
#define SCHED() __builtin_amdgcn_sched_barrier(0)
#define WAITALL_BAR()                                                         \
  {                                                                           \
    asm volatile("s_waitcnt vmcnt(0) lgkmcnt(0)" ::: "memory");               \
    SCHED(); BAR(); SCHED();                                                  \
  }

  const int xrow = t >> 2;                 // 0..63
  const int xseg = (t & 3) << 4;           // 0/16/32/48
  const float* xb0 = x + (size_t)(n0 + xrow) * 256 + xseg;
  const float* xb1 = xb0 + 64 * 256;
  float4 xr[8];

#define LOAD_X(KC)                                                            \
  {                                                                           \
    _Pragma("unroll")                                                         \
    for (int j = 0; j < 4; ++j) xr[j]     = *(const float4*)(xb0 + (KC) * 64 + j * 4); \
    _Pragma("unroll")                                                         \
    for (int j = 0; j < 4; ++j) xr[4 + j] = *(const float4*)(xb1 + (KC) * 64 + j * 4); \
  }

#define CVT_AX()                                                              \
  {                                                                           \
    _Pragma("unroll")                                                         \
    for (int hf = 0; hf < 2; ++hf) {                                          \
      u16x8 hv0, hv1, lv0, lv1;                                               \
      _Pragma("unroll")                                                       \
      for (int j = 0; j < 2; ++j) {                                           \
        float f4[8] = {xr[hf*4 + j*2].x, xr[hf*4 + j*2].y, xr[hf*4 + j*2].z,  \
                       xr[hf*4 + j*2].w, xr[hf*4 + j*2 + 1].x,                \
                       xr[hf*4 + j*2 + 1].y, xr[hf*4 + j*2 + 1].z,            \
                       xr[hf*4 + j*2 + 1].w};                                 \
        _Pragma("unroll")                                                     \
        for (int e = 0; e < 8; ++e) {                                         \
          ushort_t hi = f2bf(f4[e]);                                          \
          if (j == 0) { hv0[e] = hi; lv0[e] = f2bf(f4[e] - bf2f(hi)); }       \
          else        { hv1[e] = hi; lv1[e] = f2bf(f4[e] - bf2f(hi)); }       \
        }                                                                     \
      }                                                                       \
      int ro = hf * 64 + xrow;                                                \
      *(u16x8*)&Axh[ro * 72 + xseg]     = hv0;                                \
      *(u16x8*)&Axh[ro * 72 + xseg + 8] = hv1;                                \
      *(u16x8*)&Axl[ro * 72 + xseg]     = lv0;                                \
      *(u16x8*)&Axl[ro * 72 + xseg + 8] = lv1;                                \
    }                                                                         \
  }

#define SOFTMAX(ACC, ROFF)                                                    \
  {                                                                           \
    float cbv[8];                                                             \
    _Pragma("unroll")                                                         \
    for (int cj = 0; cj < 8; ++cj) cbv[cj] = cb_lds[cj * 16 + lr];            \
    _Pragma("unroll")                                                         \
    for (int r = 0; r < 4; ++r) {                                             \
      float v[8];                                                             \
      float m = -1e30f;                                                       \
      _Pragma("unroll")                                                       \
      for (int cj = 0; cj < 8; ++cj) {                                        \
        v[cj] = 2.f * (ACC)[cj][r] + cbv[cj];                                 \
        m = fmaxf(m, v[cj]);                                                  \
      }                                                                       \
      m = fmaxf(m, __shfl_xor(m, 1, 64));                                     \
      m = fmaxf(m, __shfl_xor(m, 2, 64));                                     \
      m = fmaxf(m, __shfl_xor(m, 4, 64));                                     \
      m = fmaxf(m, __shfl_xor(m, 8, 64));                                     \
      float s = 0.f;                                                          \
      _Pragma("unroll")                                                       \
      for (int cj = 0; cj < 8; ++cj) {                                        \
        v[cj] = __expf(v[cj] - m);                                            \
        s += v[cj];                                                           \
      }                                                                       \
      s += __shfl_xor(s, 1, 64);                                              \
      s += __shfl_xor(s, 2, 64);                                              \
      s += __shfl_xor(s, 4, 64);                                              \
      s += __shfl_xor(s, 8, 64);                                              \
      float inv = 1.f / s;                                                    \
      int row = (ROFF) + w * 16 + lk * 4 + r;                                 \
      _Pragma("unroll")                                                       \
      for (int cj = 0; cj < 8; ++cj)                                          \
        A2[row * 136 + cj * 16 + lr] = f2bf(v[cj] * inv);                     \
    }                                                                         \
  }

  // ---- Prologue: stage B(chunk0); x0 -> Ax ----
  cb_lds[t & 127] = cbias[h * 128 + (t & 127)];
  STAGE_BX(B0lds, 0);
  LOAD_X(0);
  f32x4 acc_x0[4], acc_x1[4];
  #pragma unroll
  for (int cj = 0; cj < 4; ++cj) {
    acc_x0[cj] = (f32x4){0.f, 0.f, 0.f, 0.f};
    acc_x1[cj] = (f32x4){0.f, 0.f, 0.f, 0.f};
  }
  CVT_AX();                                // chunk0 -> Ax (wave-local)
  WAITALL_BAR();                           // B0 ready

  // ---- R0 (chunk 0) ----
  STAGE_BX(B1lds, 1);
  LOAD_X(1);
  MFMAX(B0lds);
  CVT_AX();                                // chunk1 -> Ax (after own reads)
  WAITALL_BAR();
  // ---- R1 (chunk 1) ----
  STAGE_BX(B0lds, 2);
  LOAD_X(2);
  MFMAX(B1lds);
  CVT_AX();
  WAITALL_BAR();
  // ---- R2 (chunk 2) ----
  STAGE_BX(B1lds, 3);
  LOAD_X(3);
  MFMAX(B0lds);
  CVT_AX();
  WAITALL_BAR();
  // ---- R3 (chunk 3) ----
  STAGE_B(B0lds, ctr3T, 192, 0);
  MFMAX(B1lds);
  WAITALL_BAR();                           // Ax dead for ALL waves after this

  // ---- R4 (L0): write A1 from acc_x (wave-local), logits k 0..63 ----
  STAGE_B(B1lds, ctr3T, 192, 64);
  #pragma unroll
  for (int cj = 0; cj < 4; ++cj) {
    #pragma unroll
    for (int r = 0; r < 4; ++r) {
      int row = w * 16 + lk * 4 + r;
      int p = cj * 16 + lr;
      float v0 = acc_x0[cj][r];
      ushort_t hi0 = f2bf(v0);
      A1[row * 136 + p] = hi0;
      A1[row * 136 + 64 + p] = f2bf(v0 - bf2f(hi0));
      float v1 = acc_x1[cj][r];
      ushort_t hi1 = f2bf(v1);
      A1[(64 + row) * 136 + p] = hi1;
      A1[(64 + row) * 136 + 64 + p] = f2bf(v1 - bf2f(hi1));
    }
  }
  f32x4 acc0[8], acc1[8];
  #pragma unroll
  for (int cj = 0; cj < 8; ++cj) {
    acc0[cj] = (f32x4){0.f, 0.f, 0.f, 0.f};
    acc1[cj] = (f32x4){0.f, 0.f, 0.f, 0.f};
  }
  MFMA_STEP(B0lds, acc0, acc1, 0, 1);      // L0 (A1 same-wave, in-order DS)
  WAITALL_BAR();
  // ---- R5 (L1) ----
  STAGE_B(B0lds, ctr3T, 192, 128);
  MFMA_STEP(B1lds, acc0, acc1, 64, 1);     // L1
  WAITALL_BAR();
  // ---- R6 (L2) ----
  STAGE_B(B1lds, W2bT, 128, 0);
  MFMA_STEP(B0lds, acc0, acc1, 128, 1);    // L2
  WAITALL_BAR();
  // ---- R7 (softmax + T0) ----
  STAGE_B(B0lds, W2bT, 128, 64);
  SOFTMAX(acc0, 0);                        // A2 over A1: same-wave rows only
  SOFTMAX(acc1, 64);
  f32x4 accT0[8], accT1[8];
  #pragma unroll
  for (int cj = 0; cj < 8; ++cj) {
    accT0[cj] = (f32x4){0.f, 0.f, 0.f, 0.f};
    accT1[cj] = (f32x4){0.f, 0.f, 0.f, 0.f};
  }
  MFMA_STEP(B1lds, accT0, accT1, 0, 0);    // T0 (A2 same-wave, in-order DS)
  WAITALL_BAR();
  // ---- R8 (T1 + epilogue) ----
  MFMA_STEP(B0lds, accT0, accT1, 64, 0);   // T1
  // ho = xin(f32 regs)*t1 + t2 ; bounce both tiles via B1lds (free since R7)
  #pragma unroll
  for (int cj = 0; cj < 4; ++cj) {
    #pragma unroll
    for (int r = 0; r < 4; ++r) {
      int row = w * 16 + lk * 4 + r;
      int p = cj * 16 + lr;
      float hov0 = acc_x0[cj][r] * accT0[cj][r] + accT0[cj + 4][r];
      ((ushort_t*)B1lds)[row * 64 + p] = f2bf(hov0);
      float hov1 = acc_x1[cj][r] * accT1[cj][r] + accT1[cj + 4][r];
      ((ushort_t*)B1lds)[(64 + row) * 64 + p] = f2bf(hov1);
    }
  }
  asm volatile("s_waitcnt lgkmcnt(0)" ::: "memory");
  SCHED(); BAR(); SCHED();
  #pragma unroll
  for (int i = 0; i < 4; ++i) {
    int q = i * 256 + t;
    int row = q >> 3, s = q & 7;
    uint4 v = *(const uint4*)((const char*)B1lds + row * 128 + s * 16);
    *(uint4*)(ho2 + ((size_t)h * NROWS + n0 + row) * 64 + s * 8) = v;
  }
#undef STAGE_B
#undef STAGE_BX
#undef MFMA_STEP
#undef MFMAX
#undef BAR
#undef SCHED
#undef WAITALL_BAR
#undef LOAD_X
#undef CVT_AX
#undef SOFTMAX
}

// ---------------------------------------------------------------------------
extern "C" void kernel_launch(void* const* d_in, const int* in_sizes, int n_in,
                              void* d_out, int out_size, void* d_ws, size_t ws_size,
                              hipStream_t stream) {
  (void)in_sizes; (void)n_in; (void)out_size; (void)ws_size;
  const float* x    = (const float*)d_in[0];
  const float* ctrs = (const float*)d_in[1];
  const float* Wv   = (const float*)d_in[2];
  const float* Ov   = (const float*)d_in[3];
  const float* Wq   = (const float*)d_in[4];
  const float* Wo   = (const float*)d_in[5];
  float* out = (float*)d_out;

  char* wsb = (char*)d_ws;
  ushort_t* wcvtT = (ushort_t*)wsb;                   // [0, 524288)
  ushort_t* ctr3T = (ushort_t*)(wsb + 524288);        // [524288, 917504)
  float*    cb    = (float*)   (wsb + 917504);        // [917504, 921600)
  ushort_t* W2bT  = (ushort_t*)(wsb + 921600);        // [921600, 1183744)
  ushort_t* WoT   = (ushort_t*)(wsb + 1183744);       // [1183744, 1445888)
  ushort_t* ho2   = (ushort_t*)(wsb + 2097152);       // [2 MiB, 2 MiB + 8 MiB)

  prep_kernel<<<1536, 256, 0, stream>>>(Wq, ctrs, Wo, Wv, Ov,
                                        wcvtT, ctr3T, cb, WoT, W2bT);
  fused_pair_kernel<<<512, 256, 0, stream>>>(x, wcvtT, ctr3T, cb, W2bT, ho2);
  gemm2_kernel<<<512, 256, 0, stream>>>(ho2, WoT, out);
}

// Round 15
// 40.978 us; speedup vs baseline: 1.1079x; 1.0471x over previous
//
#include <hip/hip_runtime.h>
#include <math.h>

#define NROWS 8192
#define DIN   256
#define NH    8
#define NC    128
#define DOUT  256

typedef unsigned short ushort_t;
typedef __attribute__((ext_vector_type(8))) short bf16x8;
typedef __attribute__((ext_vector_type(4))) float f32x4;
typedef __attribute__((ext_vector_type(8))) unsigned short u16x8;

static __device__ __forceinline__ ushort_t f2bf(float f) {
  union { float f; unsigned u; } v; v.f = f;
  unsigned r = v.u + 0x7fffu + ((v.u >> 16) & 1u);
  return (ushort_t)(r >> 16);
}
static __device__ __forceinline__ float bf2f(ushort_t h) {
  union { unsigned u; float f; } v; v.u = ((unsigned)h) << 16;
  return v.f;
}

#define MFMA16(a, b, c) __builtin_amdgcn_mfma_f32_16x16x32_bf16((a), (b), (c), 0, 0, 0)
#define GLOAD_LDS16(g, l)                                                     \
  __builtin_amdgcn_global_load_lds(                                           \
      (const __attribute__((address_space(1))) void*)(g),                     \
      (__attribute__((address_space(3))) void*)(l), 16, 0, 0)

// ---------------------------------------------------------------------------
// Merged prep (grid 1536 x 256) — same as r14 except Wv loop unroll 8 -> 16
// (deeper MLP against cold-HBM latency; FP chain order unchanged).
// ---------------------------------------------------------------------------
__global__ __launch_bounds__(256) void prep_kernel(
    const float* __restrict__ Wq, const float* __restrict__ ctrs,
    const float* __restrict__ Wo, const float* __restrict__ Wv,
    const float* __restrict__ Ov, ushort_t* __restrict__ wcvtT,
    ushort_t* __restrict__ ctr3T, float* __restrict__ cbias,
    ushort_t* __restrict__ WoT, ushort_t* __restrict__ W2bT) {
  int bid = blockIdx.x;
  int t = threadIdx.x;
  if (bid < 512) {
    int j = bid, k = t;
    int h = j >> 6, p = j & 63;
    float v = Wq[((size_t)k * 64 + p) * 8 + h];
    ushort_t hi = f2bf(v), lo = f2bf(v - bf2f(hi));
    wcvtT[(size_t)j * 512 + k]       = hi;
    wcvtT[(size_t)j * 512 + 256 + k] = lo;
  } else if (bid < 768) {
    int idx = (bid - 512) * 4 + (t >> 6);   // h*128+c
    int p = t & 63;
    float v = ctrs[(size_t)idx * 64 + p];
    float sq = v * v;
    #pragma unroll
    for (int off = 32; off >= 1; off >>= 1) sq += __shfl_xor(sq, off, 64);
    if (p == 0) cbias[idx] = -sq;
    ushort_t hi = f2bf(v), lo = f2bf(v - bf2f(hi));
    ctr3T[(size_t)idx * 192 + p]       = hi;
    ctr3T[(size_t)idx * 192 + 64 + p]  = lo;
    ctr3T[(size_t)idx * 192 + 128 + p] = hi;
  } else if (bid < 1280) {
    int k = bid - 768;    // 0..511
    int n = t;            // 0..255
    WoT[(size_t)n * 512 + k] = f2bf(Wo[(size_t)k * 256 + n]);
  } else {
    int b = (bid - 1280) * 4 + (t >> 6);   // h*128 + c
    int p = t & 63;
    int h = b >> 7, c = b & 127;
    const float* wv = Wv + (size_t)b * 4096;
    float acc = 0.f;
    #pragma unroll 16
    for (int g = 0; g < 64; ++g) acc += wv[g * 64 + p];
    W2bT[((size_t)h * 128 + p) * 128 + c]      = f2bf(acc);
    W2bT[((size_t)h * 128 + 64 + p) * 128 + c] = f2bf(Ov[(size_t)b * 64 + p]);
  }
}

// ---------------------------------------------------------------------------
// gemm2 v2: BM=32, BN=64 -> 1024 blocks (4/CU, 16 waves/CU) for latency
// hiding. Per-output k-accumulation order identical to r12 -> bit-identical.
// 4 waves as 2x2, wave tile 16x32. LDS 12 KB.
// ---------------------------------------------------------------------------
__global__ __launch_bounds__(256) void gemm2_kernel(
    const ushort_t* __restrict__ A, const ushort_t* __restrict__ Bt,
    float* __restrict__ out) {
  __shared__ ushort_t At[32 * 64];
  __shared__ ushort_t Bl[64 * 64];
  const int t = threadIdx.x;
  const int w = t >> 6, l = t & 63;
  const int wr = w >> 1, wc = w & 1;
  const int m0 = (blockIdx.x >> 2) * 32, n0 = (blockIdx.x & 3) * 64;
  const int lr = l & 15, lk = l >> 4;

  f32x4 acc[2];
  #pragma unroll
  for (int b = 0; b < 2; ++b) acc[b] = (f32x4){0.f, 0.f, 0.f, 0.f};

  for (int k0 = 0; k0 < 512; k0 += 64) {
    // A tile 32x64: 256 chunks, 1/thread
    {
      int q = w * 64 + l;
      int row = q >> 3, s = q & 7;
      int kl = k0 + ((s ^ (row & 7)) << 3);
      GLOAD_LDS16(A + (size_t)(m0 + row) * 512 + kl,
                  (char*)At + (size_t)w * 1024);
    }
    // B tile 64x64: 512 chunks, 2/thread
    #pragma unroll
    for (int i = 0; i < 2; ++i) {
      int q = (i * 4 + w) * 64 + l;
      int row = q >> 3, s = q & 7;
      int kl = k0 + ((s ^ (row & 7)) << 3);
      GLOAD_LDS16(Bt + (size_t)(n0 + row) * 512 + kl,
                  (char*)Bl + (size_t)(i * 4 + w) * 1024);
    }
    __syncthreads();
    #pragma unroll
    for (int kk = 0; kk < 2; ++kk) {
      int rowa = wr * 16 + lr;
      int sa = (kk * 4 + lk) ^ (rowa & 7);
      bf16x8 af = *(const bf16x8*)((const char*)At + rowa * 128 + sa * 16);
      #pragma unroll
      for (int b = 0; b < 2; ++b) {
        int row = wc * 32 + b * 16 + lr;
        int s = (kk * 4 + lk) ^ (row & 7);
        bf16x8 bfr = *(const bf16x8*)((const char*)Bl + row * 128 + s * 16);
        acc[b] = MFMA16(af, bfr, acc[b]);
      }
    }
    __syncthreads();
  }
  #pragma unroll
  for (int b = 0; b < 2; ++b) {
    #pragma unroll
    for (int r = 0; r < 4; ++r) {
      int rowg = m0 + wr * 16 + lk * 4 + r;
      int colg = n0 + wc * 32 + b * 16 + lr;
      out[(size_t)rowg * 256 + colg] = acc[b][r];
    }
  }
}

// ---------------------------------------------------------------------------
// Fused-pair v3 — byte-identical to r14 (proven 42.9 µs).
// ---------------------------------------------------------------------------
__global__ __launch_bounds__(256, 2) void fused_pair_kernel(
    const float* __restrict__ x,          // [8192][256] f32
    const ushort_t* __restrict__ wcvtT,   // [512][512] hi|lo
    const ushort_t* __restrict__ ctr3T,   // [1024][192]
    const float* __restrict__ cbias,      // [1024]
    const ushort_t* __restrict__ W2bT,    // [1024][128]
    ushort_t* __restrict__ ho2) {         // flat (h,N,p)
  __shared__ __align__(16) char Au_raw[36864];
  __shared__ char B0lds[16384];
  __shared__ char B1lds[16384];
  __shared__ float cb_lds[128];

  ushort_t* Axh = (ushort_t*)Au_raw;             // [128][72]
  ushort_t* Axl = (ushort_t*)(Au_raw + 18432);   // [128][72]
  ushort_t* A1  = (ushort_t*)Au_raw;             // [128][136]
  ushort_t* A2  = (ushort_t*)Au_raw;             // [128][136]

  const int t = threadIdx.x;
  const int w = t >> 6, l = t & 63;
  const int lr = l & 15, lk = l >> 4;
  const int h = blockIdx.x >> 6;                 // 8 heads x 64 pairs
  const int n0 = (blockIdx.x & 63) * 128;

#define STAGE_B(BUF, SRC, LDB, KOFF)                                          \
  {                                                                           \
    _Pragma("unroll")                                                         \
    for (int i = 0; i < 4; ++i) {                                             \
      int q = (i * 4 + w) * 64 + l;                                           \
      int row = q >> 3, s = q & 7;                                            \
      GLOAD_LDS16((SRC) + (size_t)(h * 128 + row) * (LDB) + (KOFF) +          \
                      ((s ^ (row & 7)) << 3),                                 \
                  (char*)(BUF) + (size_t)(i * 4 + w) * 1024);                 \
    }                                                                         \
  }

#define STAGE_BX(BUF, KC)                                                     \
  {                                                                           \
    _Pragma("unroll")                                                         \
    for (int i = 0; i < 4; ++i) {                                             \
      int q = (i * 4 + w) * 64 + l;                                           \
      int row = q >> 3, s = q & 7;                                            \
      int sw = (s ^ (row & 7)) << 3;                                          \
      int jj = h * 64 + (row & 63);                                           \
      int koff = (row < 64 ? 0 : 256) + (KC) * 64 + sw;                       \
      GLOAD_LDS16(wcvtT + (size_t)jj * 512 + koff,                            \
                  (char*)(BUF) + (size_t)(i * 4 + w) * 1024);                 \
    }                                                                         \
  }

#define MFMA_STEP(BUF, ACC0, ACC1, KBASE, ASPLIT)                             \
  {                                                                           \
    _Pragma("unroll")                                                         \
    for (int kk = 0; kk < 2; ++kk) {                                          \
      int klog = (KBASE) + kk * 32 + lk * 8;                                  \
      int kp = (ASPLIT) ? (klog < 64 ? klog : klog - 64) : klog;              \
      bf16x8 af0 = *(const bf16x8*)&A1[(w * 16 + lr) * 136 + kp];             \
      bf16x8 af1 = *(const bf16x8*)&A1[(64 + w * 16 + lr) * 136 + kp];        \
      _Pragma("unroll")                                                       \
      for (int cj = 0; cj < 8; ++cj) {                                        \
        int brow = cj * 16 + lr;                                              \
        int slot = (kk * 4 + lk) ^ (brow & 7);                                \
        bf16x8 bfr =                                                          \
            *(const bf16x8*)((const char*)(BUF) + brow * 128 + slot * 16);    \
        (ACC0)[cj] = MFMA16(af0, bfr, (ACC0)[cj]);                            \
        (ACC1)[cj] = MFMA16(af1, bfr, (ACC1)[cj]);                            \
      }                                                                       \
    }                                                                         \
  }

#define MFMAX(BUF)                                                            \
  {                                                                           \
    _Pragma("unroll")                                                         \
    for (int kk = 0; kk < 2; ++kk) {                                          \
      bf16x8 ah0 = *(const bf16x8*)&Axh[(w * 16 + lr) * 72 + kk * 32 + lk * 8];     \
      bf16x8 al0 = *(const bf16x8*)&Axl[(w * 16 + lr) * 72 + kk * 32 + lk * 8];     \
      bf16x8 ah1 = *(const bf16x8*)&Axh[(64 + w * 16 + lr) * 72 + kk * 32 + lk * 8];\
      bf16x8 al1 = *(const bf16x8*)&Axl[(64 + w * 16 + lr) * 72 + kk * 32 + lk * 8];\
      _Pragma("unroll")                                                       \
      for (int cj = 0; cj < 4; ++cj) {                                        \
        int rh = cj * 16 + lr;                                                \
        int slot = (kk * 4 + lk) ^ (rh & 7);                                  \
        bf16x8 bh = *(const bf16x8*)((const char*)(BUF) + rh * 128 + slot * 16);\
        bf16x8 bl = *(const bf16x8*)((const char*)(BUF) + (64 + rh) * 128 + slot * 16);\
        acc_x0[cj] = MFMA16(ah0, bh, acc_x0[cj]);                             \
        acc_x0[cj] = MFMA16(al0, bh, acc_x0[cj]);                             \
        acc_x0[cj] = MFMA16(ah0, bl, acc_x0[cj]);                             \
        acc_x1[cj] = MFMA16(ah1, bh, acc_x1[cj]);                             \
        acc_x1[cj] = MFMA16(al1, bh, acc_x1[cj]);                             \
        acc_x1[cj] = MFMA16(ah1, bl, acc_x1[cj]);                             \
      }                                                                       \
    }                                                                         \
  }

#define BAR() __builtin_amdgcn_s_barrier()
#define SCHED() __builtin_amdgcn_sched_barrier(0)
#define WAITALL_BAR()                                                         \
  {                                                                           \
    asm volatile("s_waitcnt vmcnt(0) lgkmcnt(0)" ::: "memory");               \
    SCHED(); BAR(); SCHED();                                                  \
  }

  const int xrow = t >> 2;                 // 0..63
  const int xseg = (t & 3) << 4;           // 0/16/32/48
  const float* xb0 = x + (size_t)(n0 + xrow) * 256 + xseg;
  const float* xb1 = xb0 + 64 * 256;
  float4 xr[8];

#define LOAD_X(KC)                                                            \
  {                                                                           \
    _Pragma("unroll")                                                         \
    for (int j = 0; j < 4; ++j) xr[j]     = *(const float4*)(xb0 + (KC) * 64 + j * 4); \
    _Pragma("unroll")                                                         \
    for (int j = 0; j < 4; ++j) xr[4 + j] = *(const float4*)(xb1 + (KC) * 64 + j * 4); \
  }

#define CVT_AX()                                                              \
  {                                                                           \
    _Pragma("unroll")                                                         \
    for (int hf = 0; hf < 2; ++hf) {                                          \
      u16x8 hv0, hv1, lv0, lv1;                                               \
      _Pragma("unroll")                                                       \
      for (int j = 0; j < 2; ++j) {                                           \
        float f4[8] = {xr[hf*4 + j*2].x, xr[hf*4 + j*2].y, xr[hf*4 + j*2].z,  \
                       xr[hf*4 + j*2].w, xr[hf*4 + j*2 + 1].x,                \
                       xr[hf*4 + j*2 + 1].y, xr[hf*4 + j*2 + 1].z,            \
                       xr[hf*4 + j*2 + 1].w};                                 \
        _Pragma("unroll")                                                     \
        for (int e = 0; e < 8; ++e) {                                         \
          ushort_t hi = f2bf(f4[e]);                                          \
          if (j == 0) { hv0[e] = hi; lv0[e] = f2bf(f4[e] - bf2f(hi)); }       \
          else        { hv1[e] = hi; lv1[e] = f2bf(f4[e] - bf2f(hi)); }       \
        }                                                                     \
      }                                                                       \
      int ro = hf * 64 + xrow;                                                \
      *(u16x8*)&Axh[ro * 72 + xseg]     = hv0;                                \
      *(u16x8*)&Axh[ro * 72 + xseg + 8] = hv1;                                \
      *(u16x8*)&Axl[ro * 72 + xseg]     = lv0;                                \
      *(u16x8*)&Axl[ro * 72 + xseg + 8] = lv1;                                \
    }                                                                         \
  }

#define SOFTMAX(ACC, ROFF)                                                    \
  {                                                                           \
    float cbv[8];                                                             \
    _Pragma("unroll")                                                         \
    for (int cj = 0; cj < 8; ++cj) cbv[cj] = cb_lds[cj * 16 + lr];            \
    _Pragma("unroll")                                                         \
    for (int r = 0; r < 4; ++r) {                                             \
      float v[8];                                                             \
      float m = -1e30f;                                                       \
      _Pragma("unroll")                                                       \
      for (int cj = 0; cj < 8; ++cj) {                                        \
        v[cj] = 2.f * (ACC)[cj][r] + cbv[cj];                                 \
        m = fmaxf(m, v[cj]);                                                  \
      }                                                                       \
      m = fmaxf(m, __shfl_xor(m, 1, 64));                                     \
      m = fmaxf(m, __shfl_xor(m, 2, 64));                                     \
      m = fmaxf(m, __shfl_xor(m, 4, 64));                                     \
      m = fmaxf(m, __shfl_xor(m, 8, 64));                                     \
      float s = 0.f;                                                          \
      _Pragma("unroll")                                                       \
      for (int cj = 0; cj < 8; ++cj) {                                        \
        v[cj] = __expf(v[cj] - m);                                            \
        s += v[cj];                                                           \
      }                                                                       \
      s += __shfl_xor(s, 1, 64);                                              \
      s += __shfl_xor(s, 2, 64);                                              \
      s += __shfl_xor(s, 4, 64);                                              \
      s += __shfl_xor(s, 8, 64);                                              \
      float inv = 1.f / s;                                                    \
      int row = (ROFF) + w * 16 + lk * 4 + r;                                 \
      _Pragma("unroll")                                                       \
      for (int cj = 0; cj < 8; ++cj)                                          \
        A2[row * 136 + cj * 16 + lr] = f2bf(v[cj] * inv);                     \
    }                                                                         \
  }

  // ---- Prologue: stage B(chunk0); x0 -> Ax ----
  cb_lds[t & 127] = cbias[h * 128 + (t & 127)];
  STAGE_BX(B0lds, 0);
  LOAD_X(0);
  f32x4 acc_x0[4], acc_x1[4];
  #pragma unroll
  for (int cj = 0; cj < 4; ++cj) {
    acc_x0[cj] = (f32x4){0.f, 0.f, 0.f, 0.f};
    acc_x1[cj] = (f32x4){0.f, 0.f, 0.f, 0.f};
  }
  CVT_AX();                                // chunk0 -> Ax (wave-local)
  WAITALL_BAR();                           // B0 ready

  // ---- R0 (chunk 0) ----
  STAGE_BX(B1lds, 1);
  LOAD_X(1);
  MFMAX(B0lds);
  CVT_AX();                                // chunk1 -> Ax (after own reads)
  WAITALL_BAR();
  // ---- R1 (chunk 1) ----
  STAGE_BX(B0lds, 2);
  LOAD_X(2);
  MFMAX(B1lds);
  CVT_AX();
  WAITALL_BAR();
  // ---- R2 (chunk 2) ----
  STAGE_BX(B1lds, 3);
  LOAD_X(3);
  MFMAX(B0lds);
  CVT_AX();
  WAITALL_BAR();
  // ---- R3 (chunk 3) ----
  STAGE_B(B0lds, ctr3T, 192, 0);
  MFMAX(B1lds);
  WAITALL_BAR();                           // Ax dead for ALL waves after this

  // ---- R4 (L0): write A1 from acc_x (wave-local), logits k 0..63 ----
  STAGE_B(B1lds, ctr3T, 192, 64);
  #pragma unroll
  for (int cj = 0; cj < 4; ++cj) {
    #pragma unroll
    for (int r = 0; r < 4; ++r) {
      int row = w * 16 + lk * 4 + r;
      int p = cj * 16 + lr;
      float v0 = acc_x0[cj][r];
      ushort_t hi0 = f2bf(v0);
      A1[row * 136 + p] = hi0;
      A1[row * 136 + 64 + p] = f2bf(v0 - bf2f(hi0));
      float v1 = acc_x1[cj][r];
      ushort_t hi1 = f2bf(v1);
      A1[(64 + row) * 136 + p] = hi1;
      A1[(64 + row) * 136 + 64 + p] = f2bf(v1 - bf2f(hi1));
    }
  }
  f32x4 acc0[8], acc1[8];
  #pragma unroll
  for (int cj = 0; cj < 8; ++cj) {
    acc0[cj] = (f32x4){0.f, 0.f, 0.f, 0.f};
    acc1[cj] = (f32x4){0.f, 0.f, 0.f, 0.f};
  }
  MFMA_STEP(B0lds, acc0, acc1, 0, 1);      // L0 (A1 same-wave, in-order DS)
  WAITALL_BAR();
  // ---- R5 (L1) ----
  STAGE_B(B0lds, ctr3T, 192, 128);
  MFMA_STEP(B1lds, acc0, acc1, 64, 1);     // L1
  WAITALL_BAR();
  // ---- R6 (L2) ----
  STAGE_B(B1lds, W2bT, 128, 0);
  MFMA_STEP(B0lds, acc0, acc1, 128, 1);    // L2
  WAITALL_BAR();
  // ---- R7 (softmax + T0) ----
  STAGE_B(B0lds, W2bT, 128, 64);
  SOFTMAX(acc0, 0);                        // A2 over A1: same-wave rows only
  SOFTMAX(acc1, 64);
  f32x4 accT0[8], accT1[8];
  #pragma unroll
  for (int cj = 0; cj < 8; ++cj) {
    accT0[cj] = (f32x4){0.f, 0.f, 0.f, 0.f};
    accT1[cj] = (f32x4){0.f, 0.f, 0.f, 0.f};
  }
  MFMA_STEP(B1lds, accT0, accT1, 0, 0);    // T0 (A2 same-wave, in-order DS)
  WAITALL_BAR();
  // ---- R8 (T1 + epilogue) ----
  MFMA_STEP(B0lds, accT0, accT1, 64, 0);   // T1
  // ho = xin(f32 regs)*t1 + t2 ; bounce both tiles via B1lds (free since R7)
  #pragma unroll
  for (int cj = 0; cj < 4; ++cj) {
    #pragma unroll
    for (int r = 0; r < 4; ++r) {
      int row = w * 16 + lk * 4 + r;
      int p = cj * 16 + lr;
      float hov0 = acc_x0[cj][r] * accT0[cj][r] + accT0[cj + 4][r];
      ((ushort_t*)B1lds)[row * 64 + p] = f2bf(hov0);
      float hov1 = acc_x1[cj][r] * accT1[cj][r] + accT1[cj + 4][r];
      ((ushort_t*)B1lds)[(64 + row) * 64 + p] = f2bf(hov1);
    }
  }
  asm volatile("s_waitcnt lgkmcnt(0)" ::: "memory");
  SCHED(); BAR(); SCHED();
  #pragma unroll
  for (int i = 0; i < 4; ++i) {
    int q = i * 256 + t;
    int row = q >> 3, s = q & 7;
    uint4 v = *(const uint4*)((const char*)B1lds + row * 128 + s * 16);
    *(uint4*)(ho2 + ((size_t)h * NROWS + n0 + row) * 64 + s * 8) = v;
  }
#undef STAGE_B
#undef STAGE_BX
#undef MFMA_STEP
#undef MFMAX
#undef BAR
#undef SCHED
#undef WAITALL_BAR
#undef LOAD_X
#undef CVT_AX
#undef SOFTMAX
}

// ---------------------------------------------------------------------------
extern "C" void kernel_launch(void* const* d_in, const int* in_sizes, int n_in,
                              void* d_out, int out_size, void* d_ws, size_t ws_size,
                              hipStream_t stream) {
  (void)in_sizes; (void)n_in; (void)out_size; (void)ws_size;
  const float* x    = (const float*)d_in[0];
  const float* ctrs = (const float*)d_in[1];
  const float* Wv   = (const float*)d_in[2];
  const float* Ov   = (const float*)d_in[3];
  const float* Wq   = (const float*)d_in[4];
  const float* Wo   = (const float*)d_in[5];
  float* out = (float*)d_out;

  char* wsb = (char*)d_ws;
  ushort_t* wcvtT = (ushort_t*)wsb;                   // [0, 524288)
  ushort_t* ctr3T = (ushort_t*)(wsb + 524288);        // [524288, 917504)
  float*    cb    = (float*)   (wsb + 917504);        // [917504, 921600)
  ushort_t* W2bT  = (ushort_t*)(wsb + 921600);        // [921600, 1183744)
  ushort_t* WoT   = (ushort_t*)(wsb + 1183744);       // [1183744, 1445888)
  ushort_t* ho2   = (ushort_t*)(wsb + 2097152);       // [2 MiB, 2 MiB + 8 MiB)

  prep_kernel<<<1536, 256, 0, stream>>>(Wq, ctrs, Wo, Wv, Ov,
                                        wcvtT, ctr3T, cb, WoT, W2bT);
  fused_pair_kernel<<<512, 256, 0, stream>>>(x, wcvtT, ctr3T, cb, W2bT, ho2);
  gemm2_kernel<<<1024, 256, 0, stream>>>(ho2, WoT, out);
}